// Round 1
// 654.519 us; speedup vs baseline: 1.0063x; 1.0063x over previous
//
#include <hip/hip_runtime.h>
#include <math.h>

#define BATCH 2048
#define FID 65536
#define NT 256
#define NV (FID / 4)           // 16384 vf4 per row

typedef float vf4 __attribute__((ext_vector_type(4)));

// R10: restructure lr_partial -> lr_row. Accounting showed R9's lr_partial ran
// ~320 us (~1.7 TB/s) while the harness's 2 GiB poison fill in the same timed
// window sustained 6.5 TB/s. Theory: 2048 blocks x 4 row-streams = 8192
// concurrent 64-KiB nt streams thrash DRAM page locality. New shape: one block
// per row (grid 2048 = exact resident capacity at 8 blocks/CU), each block a
// single long sequential 256-KiB stream -- the copy-ubench pattern that hits
// 6.29 TB/s. Bias re-read per block is L1/L2-broadcast (all blocks walk the
// same bias addresses in lockstep; 256 KiB fits per-XCD L2). Row ownership is
// exclusive -> no atomicAdd, no logits memset node.
// Keep nt on gate (R7: removing nt cost +29 us), plain load on bias (wants L2).
__global__ __launch_bounds__(NT, 8) void lr_row(
        const float* __restrict__ gate,
        const float* __restrict__ bias,
        float* __restrict__ out) {          // logits region
    const int r = blockIdx.x;
    const vf4* __restrict__ b4 = (const vf4*)bias;
    const vf4* __restrict__ g4 = (const vf4*)gate + (size_t)r * NV;

    float a = 0.f;
    // 64 iterations exactly (16384/256); unroll 4 -> 8 vf4 in flight
    // (32 VGPR), fits the 64-VGPR budget of __launch_bounds__(256,8).
    #pragma unroll 4
    for (int i = threadIdx.x; i < NV; i += NT) {
        vf4 v = b4[i];
        vf4 g = __builtin_nontemporal_load(&g4[i]);
        a = fmaf(g.x, v.x, a);
        a = fmaf(g.y, v.y, a);
        a = fmaf(g.z, v.z, a);
        a = fmaf(g.w, v.w, a);
    }

    #pragma unroll
    for (int off = 32; off > 0; off >>= 1)
        a += __shfl_down(a, off, 64);

    __shared__ float wsum[NT / 64];
    const int wave = threadIdx.x >> 6;
    const int lane = threadIdx.x & 63;
    if (lane == 0) wsum[wave] = a;
    __syncthreads();
    if (threadIdx.x == 0)
        out[r] = wsum[0] + wsum[1] + wsum[2] + wsum[3];
}

// Finisher: add gbias, write final logits + pred, reduce loss. One block.
__global__ __launch_bounds__(NT) void lr_finish(
        const float* __restrict__ gbias,
        const float* __restrict__ label,
        float* __restrict__ out) {
    const float gb = gbias[0];
    float acc = 0.0f;
    for (int i = threadIdx.x; i < BATCH; i += NT) {
        float x = out[i] + gb;
        float l = label[i];
        out[i] = x;                                 // final logit
        out[BATCH + i] = 1.0f / (1.0f + expf(-x));  // pred
        acc += fmaxf(x, 0.0f) - x * l + log1pf(expf(-fabsf(x)));
    }
    #pragma unroll
    for (int off = 32; off > 0; off >>= 1)
        acc += __shfl_down(acc, off, 64);

    __shared__ float wsum[NT / 64];
    const int wave = threadIdx.x >> 6;
    const int lane = threadIdx.x & 63;
    if (lane == 0) wsum[wave] = acc;
    __syncthreads();
    if (threadIdx.x == 0)
        out[2 * BATCH] = wsum[0] + wsum[1] + wsum[2] + wsum[3];
}

extern "C" void kernel_launch(void* const* d_in, const int* in_sizes, int n_in,
                              void* d_out, int out_size, void* d_ws, size_t ws_size,
                              hipStream_t stream) {
    const float* gate  = (const float*)d_in[0];  // [BATCH, FID]
    const float* bias  = (const float*)d_in[1];  // [FID]
    const float* gbias = (const float*)d_in[2];  // [1]
    const float* label = (const float*)d_in[3];  // [BATCH]
    float* out = (float*)d_out;                  // [logits | pred | loss]

    // No memset: every logits slot is written exclusively by its own block.
    lr_row<<<BATCH, NT, 0, stream>>>(gate, bias, out);
    lr_finish<<<1, NT, 0, stream>>>(gbias, label, out);
}